// Round 6
// baseline (85.606 us; speedup 1.0000x reference)
//
#include <hip/hip_runtime.h>
#include <math.h>

#define EPS 1e-6f
#define CAP 1024
#define BB 64
#define LL 1024
#define CC 512
#define LCH 16
#define LPC (LL / LCH) /* 64 rows per chunk */

typedef float    f32x4 __attribute__((ext_vector_type(4)));
typedef _Float16 f16x4 __attribute__((ext_vector_type(4)));
typedef _Float16 f16x8 __attribute__((ext_vector_type(8)));

// ---------- kernel 1a: partial sums + fp16 copy of x -------------------------
__global__ __launch_bounds__(128) void k_partial_h(const float* __restrict__ x,
                          float* __restrict__ psum, float* __restrict__ psq,
                          _Float16* __restrict__ xh) {
    const int blk = blockIdx.x;            // b*LCH + ch
    const int b = blk / LCH, ch = blk % LCH;
    const int c = threadIdx.x * 4;
    const size_t base = ((size_t)b * LL + (size_t)ch * LPC) * CC + c;
    const f32x4* xp = (const f32x4*)(x + base);
    f16x4*       hp = (f16x4*)(xh + base);
    f32x4 s = (f32x4)0.f;
    f32x4 q = (f32x4)0.f;
#pragma unroll 8
    for (int l = 0; l < LPC; ++l) {
        f32x4 v = xp[(size_t)l * (CC / 4)];
        s += v;
        q += v * v;
        hp[(size_t)l * (CC / 4)] = __builtin_convertvector(v, f16x4);
    }
    *(f32x4*)(psum + (size_t)blk * CC + c) = s;
    *(f32x4*)(psq  + (size_t)blk * CC + c) = q;
}

// ---------- kernel 1b: partial sums only (fallback path) ---------------------
__global__ __launch_bounds__(128) void k_partial(const float* __restrict__ x,
                          float* __restrict__ psum, float* __restrict__ psq) {
    const int blk = blockIdx.x;
    const int b = blk / LCH, ch = blk % LCH;
    const int c = threadIdx.x * 4;
    const f32x4* xp = (const f32x4*)(x + ((size_t)b * LL + (size_t)ch * LPC) * CC + c);
    f32x4 s = (f32x4)0.f;
    f32x4 q = (f32x4)0.f;
#pragma unroll 8
    for (int l = 0; l < LPC; ++l) {
        f32x4 v = xp[(size_t)l * (CC / 4)];
        s += v;
        q += v * v;
    }
    *(f32x4*)(psum + (size_t)blk * CC + c) = s;
    *(f32x4*)(psq  + (size_t)blk * CC + c) = q;
}

// ---------- helper: reduce per-sample stats from partials --------------------
__device__ inline void reduce_stats(const float* __restrict__ psum,
                                    const float* __restrict__ psq,
                                    int b, int c4, f32x4& m, f32x4& g) {
    f32x4 s = (f32x4)0.f;
    f32x4 q = (f32x4)0.f;
#pragma unroll
    for (int ch = 0; ch < LCH; ++ch) {
        s += ((const f32x4*)(psum + (size_t)(b * LCH + ch) * CC))[c4];
        q += ((const f32x4*)(psq  + (size_t)(b * LCH + ch) * CC))[c4];
    }
    const float inv_n  = 1.0f / (float)LL;
    const float inv_n1 = 1.0f / (float)(LL - 1);
    m = s * inv_n;
#pragma unroll
    for (int j = 0; j < 4; ++j) {
        float var = (q[j] - (float)LL * m[j] * m[j]) * inv_n1;
        g[j] = sqrtf(fmaxf(var, 0.f) + EPS);
    }
}

// ---------- kernel 2 (fused): stats finalize + index + coefficients ----------
__global__ __launch_bounds__(256) void k_mid(const float* __restrict__ psum, const float* __restrict__ psq,
                      const float* __restrict__ mq, const float* __restrict__ sq,
                      const float* __restrict__ lmda, const int* __restrict__ domain,
                      const int* __restrict__ d1, const int* __restrict__ f1,
                      const int* __restrict__ offsets,
                      float* __restrict__ scale, float* __restrict__ shift) {
    __shared__ int dom_s[BB];
    __shared__ int pos_s[BB];
    __shared__ int src_s[2];
    const int tid = threadIdx.x;
    const int t = blockIdx.x * 256 + tid;   // 0..8191
    const int b = t >> 7, c4 = t & 127;

    if (tid < BB) dom_s[tid] = domain[tid];
    __syncthreads();
    if (tid < BB) {
        const int d = dom_s[tid];
        int rank = 0;
        for (int j = 0; j < tid; ++j) rank += (dom_s[j] == d) ? 1 : 0;
        pos_s[tid] = (offsets[d] + rank) & (CAP - 1);
    }
    __syncthreads();
    if (tid < 2) {
        const int bb = blockIdx.x * 2 + tid;
        const int dd = d1[bb], ff = f1[bb];
        int s = -1;
        for (int j = 0; j < BB; ++j)
            if (dom_s[j] == dd && pos_s[j] == ff) s = j;
        src_s[tid] = s;
    }
    __syncthreads();

    f32x4 m, g;
    reduce_stats(psum, psq, b, c4, m, g);

    const int s = src_s[b & 1];
    f32x4 m1, g1;
    if (s >= 0) {
        reduce_stats(psum, psq, s, c4, m1, g1);
    } else {
        const size_t base = ((size_t)d1[b] * CAP + (size_t)f1[b]) * CC + c4 * 4;
        m1 = *(const f32x4*)(mq + base);
        g1 = *(const f32x4*)(sq + base);
    }

    const float lm = lmda[b];
    const float om = 1.0f - lm;
    f32x4 sc, sh;
#pragma unroll
    for (int j = 0; j < 4; ++j) {
        const float mm = m[j] * lm + m1[j] * om;
        const float gm = g[j] * lm + g1[j] * om;
        sc[j] = gm / g[j];
        sh[j] = mm - m[j] * sc[j];
    }
    ((f32x4*)(scale + (size_t)b * CC))[c4] = sc;
    ((f32x4*)(shift + (size_t)b * CC))[c4] = sh;
}

// ---------- kernel 3a: out = xh*scale + shift (fp16 read, NT f32 stores) -----
__global__ __launch_bounds__(256) void k_out_h(const _Float16* __restrict__ xh,
                      const float* __restrict__ scale,
                      const float* __restrict__ shift, float* __restrict__ out) {
    const size_t base = (size_t)blockIdx.x * 512 + threadIdx.x; // 8-elem group idx
#pragma unroll
    for (int r = 0; r < 2; ++r) {
        const size_t e8 = base + (size_t)r * 256;  // over [B][L][C/8], < 4194304
        const int b  = (int)(e8 >> 16);            // / (L*C/8 = 65536)
        const int c8 = (int)(e8 & 63);             // % (C/8)
        const f16x8 hv = ((const f16x8*)xh)[e8];
        const f32x4 sc0 = ((const f32x4*)scale)[b * (CC / 4) + c8 * 2];
        const f32x4 sc1 = ((const f32x4*)scale)[b * (CC / 4) + c8 * 2 + 1];
        const f32x4 sh0 = ((const f32x4*)shift)[b * (CC / 4) + c8 * 2];
        const f32x4 sh1 = ((const f32x4*)shift)[b * (CC / 4) + c8 * 2 + 1];
        f32x4 o0, o1;
#pragma unroll
        for (int j = 0; j < 4; ++j) {
            o0[j] = fmaf((float)hv[j],     sc0[j], sh0[j]);
            o1[j] = fmaf((float)hv[j + 4], sc1[j], sh1[j]);
        }
        __builtin_nontemporal_store(o0, (f32x4*)out + e8 * 2);
        __builtin_nontemporal_store(o1, (f32x4*)out + e8 * 2 + 1);
    }
}

// ---------- kernel 3b: out = x*scale + shift (f32 read, fallback) ------------
__global__ __launch_bounds__(256) void k_out(const float* __restrict__ x, const float* __restrict__ scale,
                      const float* __restrict__ shift, float* __restrict__ out) {
    const size_t base = (size_t)blockIdx.x * 512 + threadIdx.x; // float4 group idx
#pragma unroll
    for (int r = 0; r < 2; ++r) {
        const size_t e = base + (size_t)r * 256;   // < 8388608
        const int b  = (int)(e >> 17);             // / (L*C/4 = 131072)
        const int c4 = (int)(e & 127);             // % (C/4)
        const f32x4 v  = ((const f32x4*)x)[e];
        const f32x4 sc = ((const f32x4*)scale)[b * (CC / 4) + c4];
        const f32x4 sh = ((const f32x4*)shift)[b * (CC / 4) + c4];
        f32x4 o;
#pragma unroll
        for (int j = 0; j < 4; ++j) o[j] = fmaf(v[j], sc[j], sh[j]);
        __builtin_nontemporal_store(o, (f32x4*)out + e);
    }
}

extern "C" void kernel_launch(void* const* d_in, const int* in_sizes, int n_in,
                              void* d_out, int out_size, void* d_ws, size_t ws_size,
                              hipStream_t stream) {
    const float* x       = (const float*)d_in[0];
    const int*   domain  = (const int*)d_in[1];
    const float* mq      = (const float*)d_in[2];
    const float* sq      = (const float*)d_in[3];
    const float* lmda    = (const float*)d_in[4];
    const int*   d1      = (const int*)d_in[5];
    const int*   f1      = (const int*)d_in[6];
    const int*   offsets = (const int*)d_in[7];
    float* out = (float*)d_out;

    // workspace layout (all 16B-aligned)
    float*    ws      = (float*)d_ws;
    float*    f_scale = ws;                  // 32768 floats
    float*    f_shift = ws + 32768;          // 32768 floats
    float*    f_psum  = ws + 65536;          // 524288 floats
    float*    f_psq   = f_psum + 524288;     // 524288 floats
    _Float16* f_xh    = (_Float16*)(f_psq + 524288);  // 33554432 halfs = 64 MB
    const size_t need_h = (size_t)(65536 + 2 * 524288) * 4 + (size_t)33554432 * 2;
    const bool use_h = ws_size >= need_h;

    if (use_h) {
        hipLaunchKernelGGL(k_partial_h, dim3(BB * LCH), dim3(128), 0, stream,
                           x, f_psum, f_psq, f_xh);
    } else {
        hipLaunchKernelGGL(k_partial, dim3(BB * LCH), dim3(128), 0, stream,
                           x, f_psum, f_psq);
    }
    hipLaunchKernelGGL(k_mid, dim3(32), dim3(256), 0, stream,
                       f_psum, f_psq, mq, sq, lmda, domain, d1, f1, offsets,
                       f_scale, f_shift);
    if (use_h) {
        hipLaunchKernelGGL(k_out_h, dim3((BB * LL * CC / 8) / 512), dim3(256), 0, stream,
                           f_xh, f_scale, f_shift, out);
    } else {
        hipLaunchKernelGGL(k_out, dim3((BB * LL * CC / 4) / 512), dim3(256), 0, stream,
                           x, f_scale, f_shift, out);
    }
}

// Round 7
// 69.997 us; speedup vs baseline: 1.2230x; 1.2230x over previous
//
#include <hip/hip_runtime.h>
#include <math.h>

#define EPS 1e-6f
#define CAP 1024
#define BB 64
#define LL 1024
#define CC 512
#define LCH 16
#define LPC (LL / LCH) /* 64 rows per chunk */

typedef float f32x4 __attribute__((ext_vector_type(4)));

// ---------- kernel 1: partial sums over l-chunks -----------------------------
// grid = BB*LCH blocks, 128 threads; thread t owns 4 consecutive c (float4)
__global__ __launch_bounds__(128) void k_partial(const float* __restrict__ x,
                          float* __restrict__ psum, float* __restrict__ psq) {
    const int blk = blockIdx.x;            // b*LCH + ch
    const int b = blk / LCH, ch = blk % LCH;
    const int c = threadIdx.x * 4;
    const f32x4* xp = (const f32x4*)(x + ((size_t)b * LL + (size_t)ch * LPC) * CC + c);
    f32x4 s = (f32x4)0.f;
    f32x4 q = (f32x4)0.f;
#pragma unroll 8
    for (int l = 0; l < LPC; ++l) {
        f32x4 v = xp[(size_t)l * (CC / 4)];
        s += v;
        q += v * v;
    }
    *(f32x4*)(psum + (size_t)blk * CC + c) = s;
    *(f32x4*)(psq  + (size_t)blk * CC + c) = q;
}

// ---------- helper: reduce per-sample stats from partials --------------------
__device__ inline void reduce_stats(const float* __restrict__ psum,
                                    const float* __restrict__ psq,
                                    int b, int c4, f32x4& m, f32x4& g) {
    f32x4 s = (f32x4)0.f;
    f32x4 q = (f32x4)0.f;
#pragma unroll
    for (int ch = 0; ch < LCH; ++ch) {
        s += ((const f32x4*)(psum + (size_t)(b * LCH + ch) * CC))[c4];
        q += ((const f32x4*)(psq  + (size_t)(b * LCH + ch) * CC))[c4];
    }
    const float inv_n  = 1.0f / (float)LL;
    const float inv_n1 = 1.0f / (float)(LL - 1);
    m = s * inv_n;
#pragma unroll
    for (int j = 0; j < 4; ++j) {
        float var = (q[j] - (float)LL * m[j] * m[j]) * inv_n1;
        g[j] = sqrtf(fmaxf(var, 0.f) + EPS);
    }
}

// ---------- kernel 2 (fused): stats finalize + index + coefficients ----------
// 32 blocks x 256 threads; thread t owns (b = t/128, c4 = t%128)
__global__ __launch_bounds__(256) void k_mid(const float* __restrict__ psum, const float* __restrict__ psq,
                      const float* __restrict__ mq, const float* __restrict__ sq,
                      const float* __restrict__ lmda, const int* __restrict__ domain,
                      const int* __restrict__ d1, const int* __restrict__ f1,
                      const int* __restrict__ offsets,
                      float* __restrict__ scale, float* __restrict__ shift) {
    __shared__ int dom_s[BB];
    __shared__ int pos_s[BB];
    __shared__ int src_s[2];
    const int tid = threadIdx.x;
    const int t = blockIdx.x * 256 + tid;   // 0..8191
    const int b = t >> 7, c4 = t & 127;

    if (tid < BB) dom_s[tid] = domain[tid];
    __syncthreads();
    if (tid < BB) {
        const int d = dom_s[tid];
        int rank = 0;
        for (int j = 0; j < tid; ++j) rank += (dom_s[j] == d) ? 1 : 0;
        pos_s[tid] = (offsets[d] + rank) & (CAP - 1);
    }
    __syncthreads();
    if (tid < 2) {
        const int bb = blockIdx.x * 2 + tid;
        const int dd = d1[bb], ff = f1[bb];
        int s = -1;
        for (int j = 0; j < BB; ++j)
            if (dom_s[j] == dd && pos_s[j] == ff) s = j;
        src_s[tid] = s;
    }
    __syncthreads();

    f32x4 m, g;
    reduce_stats(psum, psq, b, c4, m, g);

    const int s = src_s[b & 1];
    f32x4 m1, g1;
    if (s >= 0) {
        reduce_stats(psum, psq, s, c4, m1, g1);
    } else {
        const size_t base = ((size_t)d1[b] * CAP + (size_t)f1[b]) * CC + c4 * 4;
        m1 = *(const f32x4*)(mq + base);
        g1 = *(const f32x4*)(sq + base);
    }

    const float lm = lmda[b];
    const float om = 1.0f - lm;
    f32x4 sc, sh;
#pragma unroll
    for (int j = 0; j < 4; ++j) {
        const float mm = m[j] * lm + m1[j] * om;
        const float gm = g[j] * lm + g1[j] * om;
        sc[j] = gm / g[j];
        sh[j] = mm - m[j] * sc[j];
    }
    ((f32x4*)(scale + (size_t)b * CC))[c4] = sc;
    ((f32x4*)(shift + (size_t)b * CC))[c4] = sh;
}

// ---------- kernel 3: out = x*scale + shift, REVERSED block order ------------
// Block i processes the tile block (N-1-i) would: k_partial left the TAIL of x
// most-recently-cached in L3; reading tail-first turns the re-read into L3
// hits instead of chasing LRU evictions. Within-block layout unchanged
// (full coalescing). NT stores keep `out` from evicting x where supported.
__global__ __launch_bounds__(256) void k_out(const float* __restrict__ x, const float* __restrict__ scale,
                      const float* __restrict__ shift, float* __restrict__ out) {
    const int rb = (int)gridDim.x - 1 - (int)blockIdx.x;       // reversed block id
    const size_t base = (size_t)rb * 512 + threadIdx.x;        // float4 group idx
#pragma unroll
    for (int r = 0; r < 2; ++r) {
        const size_t e = base + (size_t)r * 256;   // < 8388608
        const int b  = (int)(e >> 17);             // / (L*C/4 = 131072)
        const int c4 = (int)(e & 127);             // % (C/4)
        const f32x4 v  = ((const f32x4*)x)[e];
        const f32x4 sc = ((const f32x4*)scale)[b * (CC / 4) + c4];
        const f32x4 sh = ((const f32x4*)shift)[b * (CC / 4) + c4];
        f32x4 o;
#pragma unroll
        for (int j = 0; j < 4; ++j) o[j] = fmaf(v[j], sc[j], sh[j]);
        __builtin_nontemporal_store(o, (f32x4*)out + e);
    }
}

extern "C" void kernel_launch(void* const* d_in, const int* in_sizes, int n_in,
                              void* d_out, int out_size, void* d_ws, size_t ws_size,
                              hipStream_t stream) {
    const float* x       = (const float*)d_in[0];
    const int*   domain  = (const int*)d_in[1];
    const float* mq      = (const float*)d_in[2];
    const float* sq      = (const float*)d_in[3];
    const float* lmda    = (const float*)d_in[4];
    const int*   d1      = (const int*)d_in[5];
    const int*   f1      = (const int*)d_in[6];
    const int*   offsets = (const int*)d_in[7];
    float* out = (float*)d_out;

    // workspace layout (float offsets, all 16B-aligned)
    float* ws      = (float*)d_ws;
    float* f_scale = ws;                    // 32768
    float* f_shift = ws + 32768;            // 32768
    float* f_psum  = ws + 65536;            // 524288
    float* f_psq   = f_psum + 524288;       // 524288

    hipLaunchKernelGGL(k_partial, dim3(BB * LCH), dim3(128), 0, stream,
                       x, f_psum, f_psq);
    hipLaunchKernelGGL(k_mid, dim3(32), dim3(256), 0, stream,
                       f_psum, f_psq, mq, sq, lmda, domain, d1, f1, offsets,
                       f_scale, f_shift);
    hipLaunchKernelGGL(k_out, dim3((BB * LL * CC / 4) / 512), dim3(256), 0, stream,
                       x, f_scale, f_shift, out);
}

// Round 9
// 69.411 us; speedup vs baseline: 1.2333x; 1.0084x over previous
//
#include <hip/hip_runtime.h>
#include <math.h>

#define EPS 1e-6f
#define CAP 1024
#define BB 64
#define LL 1024
#define CC 512
#define LCH 16
#define LPC (LL / LCH) /* 64 rows per chunk */

typedef float f32x4 __attribute__((ext_vector_type(4)));

// ---------- kernel 1: partial sums over l-chunks -----------------------------
// grid = BB*LCH blocks, 128 threads; thread t owns 4 consecutive c (float4)
__global__ __launch_bounds__(128) void k_partial(const float* __restrict__ x,
                          float* __restrict__ psum, float* __restrict__ psq) {
    const int blk = blockIdx.x;            // b*LCH + ch
    const int b = blk / LCH, ch = blk % LCH;
    const int c = threadIdx.x * 4;
    const f32x4* xp = (const f32x4*)(x + ((size_t)b * LL + (size_t)ch * LPC) * CC + c);
    f32x4 s = (f32x4)0.f;
    f32x4 q = (f32x4)0.f;
#pragma unroll 8
    for (int l = 0; l < LPC; ++l) {
        f32x4 v = xp[(size_t)l * (CC / 4)];
        s += v;
        q += v * v;
    }
    *(f32x4*)(psum + (size_t)blk * CC + c) = s;
    *(f32x4*)(psq  + (size_t)blk * CC + c) = q;
}

// ---------- helper: reduce per-sample stats from partials --------------------
__device__ inline void reduce_stats(const float* __restrict__ psum,
                                    const float* __restrict__ psq,
                                    int b, int c4, f32x4& m, f32x4& g) {
    f32x4 s = (f32x4)0.f;
    f32x4 q = (f32x4)0.f;
#pragma unroll
    for (int ch = 0; ch < LCH; ++ch) {
        s += ((const f32x4*)(psum + (size_t)(b * LCH + ch) * CC))[c4];
        q += ((const f32x4*)(psq  + (size_t)(b * LCH + ch) * CC))[c4];
    }
    const float inv_n  = 1.0f / (float)LL;
    const float inv_n1 = 1.0f / (float)(LL - 1);
    m = s * inv_n;
#pragma unroll
    for (int j = 0; j < 4; ++j) {
        float var = (q[j] - (float)LL * m[j] * m[j]) * inv_n1;
        g[j] = sqrtf(fmaxf(var, 0.f) + EPS);
    }
}

// ---------- kernel 2 (fused): stats finalize + index + coefficients ----------
// 32 blocks x 256 threads; thread t owns (b = t/128, c4 = t%128)
__global__ __launch_bounds__(256) void k_mid(const float* __restrict__ psum, const float* __restrict__ psq,
                      const float* __restrict__ mq, const float* __restrict__ sq,
                      const float* __restrict__ lmda, const int* __restrict__ domain,
                      const int* __restrict__ d1, const int* __restrict__ f1,
                      const int* __restrict__ offsets,
                      float* __restrict__ scale, float* __restrict__ shift) {
    __shared__ int dom_s[BB];
    __shared__ int pos_s[BB];
    __shared__ int src_s[2];
    const int tid = threadIdx.x;
    const int t = blockIdx.x * 256 + tid;   // 0..8191
    const int b = t >> 7, c4 = t & 127;

    if (tid < BB) dom_s[tid] = domain[tid];
    __syncthreads();
    if (tid < BB) {
        const int d = dom_s[tid];
        int rank = 0;
        for (int j = 0; j < tid; ++j) rank += (dom_s[j] == d) ? 1 : 0;
        pos_s[tid] = (offsets[d] + rank) & (CAP - 1);
    }
    __syncthreads();
    if (tid < 2) {
        const int bb = blockIdx.x * 2 + tid;
        const int dd = d1[bb], ff = f1[bb];
        int s = -1;
        for (int j = 0; j < BB; ++j)
            if (dom_s[j] == dd && pos_s[j] == ff) s = j;
        src_s[tid] = s;
    }
    __syncthreads();

    f32x4 m, g;
    reduce_stats(psum, psq, b, c4, m, g);

    const int s = src_s[b & 1];
    f32x4 m1, g1;
    if (s >= 0) {
        reduce_stats(psum, psq, s, c4, m1, g1);
    } else {
        const size_t base = ((size_t)d1[b] * CAP + (size_t)f1[b]) * CC + c4 * 4;
        m1 = *(const f32x4*)(mq + base);
        g1 = *(const f32x4*)(sq + base);
    }

    const float lm = lmda[b];
    const float om = 1.0f - lm;
    f32x4 sc, sh;
#pragma unroll
    for (int j = 0; j < 4; ++j) {
        const float mm = m[j] * lm + m1[j] * om;
        const float gm = g[j] * lm + g1[j] * om;
        sc[j] = gm / g[j];
        sh[j] = mm - m[j] * sc[j];
    }
    ((f32x4*)(scale + (size_t)b * CC))[c4] = sc;
    ((f32x4*)(shift + (size_t)b * CC))[c4] = sh;
}

// ---------- kernel 3: out = x*scale + shift (2 float4 / thread, NT stores) ---
__global__ __launch_bounds__(256) void k_out(const float* __restrict__ x, const float* __restrict__ scale,
                      const float* __restrict__ shift, float* __restrict__ out) {
    const size_t base = (size_t)blockIdx.x * 512 + threadIdx.x; // float4 group idx
#pragma unroll
    for (int r = 0; r < 2; ++r) {
        const size_t e = base + (size_t)r * 256;   // < 8388608
        const int b  = (int)(e >> 17);             // / (L*C/4 = 131072)
        const int c4 = (int)(e & 127);             // % (C/4)
        const f32x4 v  = ((const f32x4*)x)[e];
        const f32x4 sc = ((const f32x4*)scale)[b * (CC / 4) + c4];
        const f32x4 sh = ((const f32x4*)shift)[b * (CC / 4) + c4];
        f32x4 o;
#pragma unroll
        for (int j = 0; j < 4; ++j) o[j] = fmaf(v[j], sc[j], sh[j]);
        __builtin_nontemporal_store(o, (f32x4*)out + e);
    }
}

extern "C" void kernel_launch(void* const* d_in, const int* in_sizes, int n_in,
                              void* d_out, int out_size, void* d_ws, size_t ws_size,
                              hipStream_t stream) {
    const float* x       = (const float*)d_in[0];
    const int*   domain  = (const int*)d_in[1];
    const float* mq      = (const float*)d_in[2];
    const float* sq      = (const float*)d_in[3];
    const float* lmda    = (const float*)d_in[4];
    const int*   d1      = (const int*)d_in[5];
    const int*   f1      = (const int*)d_in[6];
    const int*   offsets = (const int*)d_in[7];
    float* out = (float*)d_out;

    // workspace layout (float offsets, all 16B-aligned)
    float* ws      = (float*)d_ws;
    float* f_scale = ws;                    // 32768
    float* f_shift = ws + 32768;            // 32768
    float* f_psum  = ws + 65536;            // 524288
    float* f_psq   = f_psum + 524288;       // 524288

    hipLaunchKernelGGL(k_partial, dim3(BB * LCH), dim3(128), 0, stream,
                       x, f_psum, f_psq);
    hipLaunchKernelGGL(k_mid, dim3(32), dim3(256), 0, stream,
                       f_psum, f_psq, mq, sq, lmda, domain, d1, f1, offsets,
                       f_scale, f_shift);
    hipLaunchKernelGGL(k_out, dim3((BB * LL * CC / 4) / 512), dim3(256), 0, stream,
                       x, f_scale, f_shift, out);
}